// Round 2
// 582.301 us; speedup vs baseline: 1.0795x; 1.0795x over previous
//
#include <hip/hip_runtime.h>

#define THREADS 256

// ---------------------------------------------------------------------------
// Plain split-K/split-H matvec (x read raw from global, dense).
// Block (kt, s, n) writes P[n][s][k0..k0+TCOLS).
// ---------------------------------------------------------------------------
template<int TCOLS>
__global__ __launch_bounds__(THREADS) void matvec_k(
    const float* __restrict__ x, const float* __restrict__ W,
    float* __restrict__ P,
    int K, int slice_h, int nslices,
    long x_stride, long w_stride)
{
    const int n = blockIdx.z;
    const float* xn = x + (long)n * x_stride;
    const float* Wn = W + (long)n * w_stride;
    float* Pn = P + ((long)n * nslices + blockIdx.y) * K;

    const int h0 = blockIdx.y * slice_h;
    constexpr int TPR = TCOLS / 4;
    constexpr int RPI = THREADS / TPR;
    const int tid = threadIdx.x;
    const int lane_r = tid % TPR;
    const int row_off = tid / TPR;
    const int c = blockIdx.x * TCOLS + 4 * lane_r;

    extern __shared__ char smem[];
    float* xs = (float*)smem;
    int*   idx = (int*)(smem + (size_t)slice_h * 4);
    __shared__ int cnt;

    if (tid == 0) cnt = 0;
    __syncthreads();
    for (int i = tid; i < slice_h; i += THREADS) {
        float v = xn[h0 + i];
        xs[i] = v;
        if (v != 0.0f) { int p = atomicAdd(&cnt, 1); idx[p] = i; }
    }
    __syncthreads();
    const int m = cnt;

    float ax = 0.f, ay = 0.f, az = 0.f, aw = 0.f;
    #pragma unroll 4
    for (int j = row_off; j < m; j += RPI) {
        const int i = idx[j];
        const float4 w4 = *(const float4*)(Wn + (long)(h0 + i) * K + c);
        const float xv = xs[i];
        ax = fmaf(xv, w4.x, ax); ay = fmaf(xv, w4.y, ay);
        az = fmaf(xv, w4.z, az); aw = fmaf(xv, w4.w, aw);
    }
    if constexpr (RPI > 1) {
        __shared__ float red[THREADS * 4];
        red[tid * 4 + 0] = ax; red[tid * 4 + 1] = ay;
        red[tid * 4 + 2] = az; red[tid * 4 + 3] = aw;
        __syncthreads();
        if (row_off == 0) {
            #pragma unroll
            for (int g = 1; g < RPI; g++) {
                const int o = (tid + g * TPR) * 4;
                ax += red[o + 0]; ay += red[o + 1];
                az += red[o + 2]; aw += red[o + 3];
            }
            float4 r; r.x = ax; r.y = ay; r.z = az; r.w = aw;
            *(float4*)(Pn + c) = r;
        }
    } else {
        float4 r; r.x = ax; r.y = ay; r.z = az; r.w = aw;
        *(float4*)(Pn + c) = r;
    }
}

// ---------------------------------------------------------------------------
// Matvec with FUSED x-build: x[i] = relu( sum_{s<NSLP} Pprev[.., h0+i] + bias ),
// then zero-skip matvec over W. Removes the standalone reduce kernels.
// SH must divide THREADS.
// ---------------------------------------------------------------------------
template<int TCOLS, int SH, bool RELU>
__global__ __launch_bounds__(THREADS) void matvec_rx(
    const float* __restrict__ Pprev, const float* __restrict__ bias,
    const float* __restrict__ W, float* __restrict__ Pout,
    int K, int nsl_prev, int prev_K, int nsl_out,
    long pprev_stride, long bias_stride, long w_stride)
{
    const int n = blockIdx.z;
    const int h0 = blockIdx.y * SH;
    const float* Pp = Pprev + (long)n * pprev_stride;
    const float* bn = bias + (long)n * bias_stride;
    const float* Wn = W + (long)n * w_stride;
    float* Pn = Pout + ((long)n * nsl_out + blockIdx.y) * K;

    constexpr int G = THREADS / SH;
    const int tid = threadIdx.x;
    __shared__ float part[THREADS];
    __shared__ float xs[SH];
    __shared__ int idx[SH];
    __shared__ int cnt;

    // x-build: (i, g) split; g strides over prev slices
    {
        const int i = tid % SH, g = tid / SH;
        float a = 0.f;
        for (int sp = g; sp < nsl_prev; sp += G)
            a += Pp[(long)sp * prev_K + h0 + i];
        part[g * SH + i] = a;
    }
    if (tid == 0) cnt = 0;
    __syncthreads();
    if (tid < SH) {
        float v = part[tid];
        #pragma unroll
        for (int g = 1; g < G; g++) v += part[g * SH + tid];
        v += bn[h0 + tid];
        if (RELU) v = fmaxf(v, 0.f);
        xs[tid] = v;
        if (v != 0.0f) { int p = atomicAdd(&cnt, 1); idx[p] = tid; }
    }
    __syncthreads();
    const int m = cnt;

    constexpr int TPR = TCOLS / 4;
    constexpr int RPI = THREADS / TPR;
    const int lane_r = tid % TPR;
    const int row_off = tid / TPR;
    const int c = blockIdx.x * TCOLS + 4 * lane_r;

    float ax = 0.f, ay = 0.f, az = 0.f, aw = 0.f;
    #pragma unroll 4
    for (int j = row_off; j < m; j += RPI) {
        const int i = idx[j];
        const float4 w4 = *(const float4*)(Wn + (long)(h0 + i) * K + c);
        const float xv = xs[i];
        ax = fmaf(xv, w4.x, ax); ay = fmaf(xv, w4.y, ay);
        az = fmaf(xv, w4.z, az); aw = fmaf(xv, w4.w, aw);
    }
    if constexpr (RPI > 1) {
        __shared__ float red[THREADS * 4];
        red[tid * 4 + 0] = ax; red[tid * 4 + 1] = ay;
        red[tid * 4 + 2] = az; red[tid * 4 + 3] = aw;
        __syncthreads();
        if (row_off == 0) {
            #pragma unroll
            for (int g = 1; g < RPI; g++) {
                const int o = (tid + g * TPR) * 4;
                ax += red[o + 0]; ay += red[o + 1];
                az += red[o + 2]; aw += red[o + 3];
            }
            float4 r; r.x = ax; r.y = ay; r.z = az; r.w = aw;
            *(float4*)(Pn + c) = r;
        }
    } else {
        float4 r; r.x = ax; r.y = ay; r.z = az; r.w = aw;
        *(float4*)(Pn + c) = r;
    }
}

// ---------------------------------------------------------------------------
// W_t matvec with fused x-build:
// x[i] = sum_n ekq[n] * ( sum_{s<32} Pv[n][s][h0+i] + b_v[n,h0+i] )
// ekq[n] = sum_j pkq[n*8+j]  (b_k.q folded into pkq[n*8+0] by kq2_k).
// g == expert.
// ---------------------------------------------------------------------------
template<int TCOLS>
__global__ __launch_bounds__(THREADS) void matvec_tx(
    const float* __restrict__ Pv, const float* __restrict__ bv,
    const float* __restrict__ pkq,
    const float* __restrict__ Wt, float* __restrict__ Pout,
    int K, int nsl_out)
{
    const int h0 = blockIdx.y * 16;
    const int tid = threadIdx.x;
    __shared__ float ekqs[16];
    __shared__ float part[THREADS];
    __shared__ float xs[16];

    if (tid < 16) {
        float e = 0.f;
        #pragma unroll
        for (int j = 0; j < 8; j++) e += pkq[tid * 8 + j];
        ekqs[tid] = e;
    }
    __syncthreads();
    {
        const int i = tid % 16, n = tid / 16;
        const float* Pp = Pv + (long)n * 32 * 2048;
        float a = 0.f;
        #pragma unroll 8
        for (int sp = 0; sp < 32; sp++) a += Pp[(long)sp * 2048 + h0 + i];
        a += bv[(long)n * 2048 + h0 + i];
        part[tid] = ekqs[n] * a;
    }
    __syncthreads();
    if (tid < 16) {
        float v = 0.f;
        #pragma unroll
        for (int g = 0; g < 16; g++) v += part[g * 16 + tid];
        xs[tid] = v;
    }
    __syncthreads();

    // dense main loop (TCOLS=1024: TPR=256, RPI=1)
    const int c = blockIdx.x * TCOLS + 4 * tid;
    float ax = 0.f, ay = 0.f, az = 0.f, aw = 0.f;
    #pragma unroll 4
    for (int i = 0; i < 16; i++) {
        const float4 w4 = *(const float4*)(Wt + (long)(h0 + i) * K + c);
        const float xv = xs[i];
        ax = fmaf(xv, w4.x, ax); ay = fmaf(xv, w4.y, ay);
        az = fmaf(xv, w4.z, az); aw = fmaf(xv, w4.w, aw);
    }
    float4 r; r.x = ax; r.y = ay; r.z = az; r.w = aw;
    *(float4*)(Pout + (long)blockIdx.y * K + c) = r;
}

// final: y[col] = sum_s P[s][col] + b[col]
template<bool RELU, bool HAS_BIAS>
__global__ __launch_bounds__(THREADS) void reduce_k(
    const float* __restrict__ P, const float* __restrict__ b,
    float* __restrict__ y, int K, int nslices)
{
    const int n = blockIdx.y;
    const int col = blockIdx.x * 64 + (threadIdx.x & 63);
    const int grp = threadIdx.x >> 6;
    const float* Pn = P + (long)n * nslices * K + col;
    float s = 0.f;
    for (int i = grp; i < nslices; i += 4) s += Pn[(long)i * K];
    __shared__ float red[4][64];
    red[grp][threadIdx.x & 63] = s;
    __syncthreads();
    if (threadIdx.x < 64) {
        float t = red[0][threadIdx.x] + red[1][threadIdx.x] +
                  red[2][threadIdx.x] + red[3][threadIdx.x];
        if (HAS_BIAS) t += b[(long)n * K + col];
        if (RELU) t = fmaxf(t, 0.f);
        y[(long)n * K + col] = t;
    }
}

// pkq[n*8+s] = sum_{h in 256-chunk s} eact[n,h] * (W_k[n,h,:] . q)
// eact built in-kernel from Pexp (32 slices) + b_exp + relu; rows skipped.
// q built in-block from W_q/b_q (2 KB, L2-hot); b_k[n].q folded into s==0.
__global__ __launch_bounds__(THREADS) void kq2_k(
    const float* __restrict__ Pexp, const float* __restrict__ bexp,
    const float* __restrict__ Wk,
    const float* __restrict__ Wq, const float* __restrict__ bq,
    const float* __restrict__ bk, const int* __restrict__ task,
    float* __restrict__ pkq)
{
    const int n = blockIdx.y, s = blockIdx.x;
    const int h0 = s * 256;
    const int tid = threadIdx.x;
    __shared__ float xs[256], qs[256];
    __shared__ int idx[256];
    __shared__ int cnt;
    __shared__ float wred[4];
    if (tid == 0) cnt = 0;
    const int t = task[0];
    qs[tid] = Wq[((long)t * 10 + t) * 256 + tid] + bq[(long)t * 256 + tid];
    const float* Pp = Pexp + (long)n * 32 * 2048;
    float a = 0.f;
    #pragma unroll 8
    for (int sp = 0; sp < 32; sp++) a += Pp[(long)sp * 2048 + h0 + tid];
    a += bexp[(long)n * 2048 + h0 + tid];
    a = fmaxf(a, 0.f);
    __syncthreads();
    xs[tid] = a;
    if (a != 0.0f) { int p = atomicAdd(&cnt, 1); idx[p] = tid; }
    __syncthreads();
    const int m = cnt;
    const int lane_r = tid & 63, row_off = tid >> 6;
    const float q0 = qs[4 * lane_r], q1 = qs[4 * lane_r + 1];
    const float q2 = qs[4 * lane_r + 2], q3 = qs[4 * lane_r + 3];
    float acc = 0.f;
    #pragma unroll 4
    for (int j = row_off; j < m; j += 4) {
        const int i = idx[j];
        const float4 w4 = *(const float4*)(Wk + ((long)n * 2048 + h0 + i) * 256 + 4 * lane_r);
        acc += xs[i] * (w4.x * q0 + w4.y * q1 + w4.z * q2 + w4.w * q3);
    }
    // fold bkq[n] = b_k[n,:].q into the s==0 partial (summed over all threads)
    if (s == 0) acc += bk[(long)n * 256 + tid] * qs[tid];
    for (int o = 32; o; o >>= 1) acc += __shfl_down(acc, o, 64);
    if ((tid & 63) == 0) wred[tid >> 6] = acc;
    __syncthreads();
    if (tid == 0) pkq[n * 8 + s] = wred[0] + wred[1] + wred[2] + wred[3];
}

extern "C" void kernel_launch(void* const* d_in, const int* in_sizes, int n_in,
                              void* d_out, int out_size, void* d_ws, size_t ws_size,
                              hipStream_t stream)
{
    const float* x    = (const float*)d_in[0];
    const float* W1   = (const float*)d_in[1];
    const float* b1   = (const float*)d_in[2];
    const float* W2   = (const float*)d_in[3];
    const float* b2   = (const float*)d_in[4];
    const float* Wexp = (const float*)d_in[5];
    const float* bexp = (const float*)d_in[6];
    const float* Wv   = (const float*)d_in[7];
    const float* bv   = (const float*)d_in[8];
    const float* Wk   = (const float*)d_in[9];
    const float* bk   = (const float*)d_in[10];
    const float* Wq   = (const float*)d_in[11];
    const float* bq   = (const float*)d_in[12];
    const float* Wt   = (const float*)d_in[13];
    const float* bt   = (const float*)d_in[14];
    const float* Wl   = (const float*)d_in[15];
    const float* bl   = (const float*)d_in[16];
    const int*   task = (const int*)d_in[17];

    // workspace layout (floats) — all written before read
    float* ws   = (float*)d_ws;
    float* P1   = ws;             // 128*2048   = 262144
    float* P2   = ws + 262144;    // 128*2048   = 262144
    float* Pexp = ws + 524288;    // 16*32*2048 = 1048576
    float* Pv   = ws + 1572864;   // 16*32*2048 = 1048576
    float* Pt   = ws + 2621440;   // 128*2048   = 262144
    float* Pl   = ws + 2883584;   // 64*512     = 32768
    float* pkq  = ws + 2916352;   // 128

    // P1 = partials of x @ W1                        (16 MB dense)
    matvec_k<1024><<<dim3(2, 128, 1), THREADS, 16 * 8, stream>>>(
        x, W1, P1, 2048, 16, 128, 0, 0);

    // P2 = partials of relu(red(P1)+b1) @ W2         (~8 MB)
    matvec_rx<1024, 16, true><<<dim3(2, 128, 1), THREADS, 0, stream>>>(
        P1, b1, W2, P2, 2048, 128, 2048, 128, 0, 0, 0);

    // Pexp[n] = partials of relu(red(P2)+b2) @ W_exp[n]   (~128 MB)
    matvec_rx<1024, 64, true><<<dim3(2, 32, 16), THREADS, 0, stream>>>(
        P2, b2, Wexp, Pexp, 2048, 128, 2048, 32, 0, 0, 2048L * 2048);

    // pkq = partials of eact . (W_k . q), q/bkq folded in   (~16 MB)
    kq2_k<<<dim3(8, 16), THREADS, 0, stream>>>(
        Pexp, bexp, Wk, Wq, bq, bk, task, pkq);

    // Pv[n] = partials of eact[n] @ W_v[n]  (no ekq yet)   (~128 MB)
    // SH=64 -> 1024 blocks (4/CU) for latency hiding.
    matvec_rx<1024, 64, true><<<dim3(2, 32, 16), THREADS, 0, stream>>>(
        Pexp, bexp, Wv, Pv, 2048, 32, 2048, 32,
        32L * 2048, 2048, 2048L * 2048);

    // Pt = partials of (sum_n ekq[n]*(red(Pv[n])+bv[n])) @ W_t   (16 MB dense)
    matvec_tx<1024><<<dim3(2, 128, 1), THREADS, 0, stream>>>(
        Pv, bv, pkq, Wt, Pt, 2048, 128);

    // Pl = partials of relu(red(Pt)+bt) @ W_l        (~2 MB)
    matvec_rx<512, 32, true><<<dim3(1, 64, 1), THREADS, 0, stream>>>(
        Pt, bt, Wl, Pl, 512, 128, 2048, 64, 0, 0, 0);

    // d_out = red(Pl) + bl
    reduce_k<false, true><<<dim3(8, 1), THREADS, 0, stream>>>(
        Pl, bl, (float*)d_out, 512, 64);
}